// Round 5
// baseline (79.565 us; speedup 1.0000x reference)
//
#include <hip/hip_runtime.h>

#define N_TOTAL   4096
#define N_NODES   1024
#define N_MARBLES 3072
#define N_EATERS  64
#define EPS       1e-6f
#define BLOCK     256
#define JCHUNK    32                  // j's per force block
#define JCHUNKS   (N_TOTAL / JCHUNK) // 128

// ---------------------------------------------------------------------------
// Kernel 1: partial accelerations.
// grid = (16, 128), block = 256 -> 2048 blocks = 8 blocks/CU = 8 waves/SIMD
// (max occupancy, hides v_rsq + s_load latency). j is wave-uniform ->
// scalar loads (s_load_dwordx2 for pos). d2==0 pairs contribute exactly 0
// (dx=dy=0, finite w), so no mask needed.
// ---------------------------------------------------------------------------
__global__ __launch_bounds__(BLOCK) void force_partial(
    const float2* __restrict__ pos2, const float* __restrict__ mass,
    float2* __restrict__ partial)
{
    const int i  = blockIdx.x * BLOCK + threadIdx.x;
    const int j0 = blockIdx.y * JCHUNK;

    const float2 pi = pos2[i];
    float ax = 0.f, ay = 0.f;

#pragma unroll
    for (int j = j0; j < j0 + JCHUNK; ++j) {
        const float2 pj = pos2[j];               // uniform -> s_load_dwordx2
        const float dx = pj.x - pi.x;
        const float dy = pj.y - pi.y;
        const float t  = fmaf(dx, dx, fmaf(dy, dy, EPS));  // d2 + EPS
        const float r  = rsqrtf(t);
        const float w  = r * r * r * mass[j];    // m_j * t^{-1.5}
        ax = fmaf(w, dx, ax);
        ay = fmaf(w, dy, ay);
    }

    partial[blockIdx.y * N_TOTAL + i] = make_float2(ax, ay);
}

// ---------------------------------------------------------------------------
// Kernel 2: integrate. grid = 64 blocks x 256 threads; each block owns 64
// particles. Wave t (of 4) sums partial chunks [32t, 32t+32) for all 64
// particles with coalesced float2 reads; LDS-reduce 4 -> 1; wave 0 does the
// Euler step and writes state_new = [pos_new; vel_new].
// ---------------------------------------------------------------------------
__global__ __launch_bounds__(BLOCK) void integrate(
    const float* __restrict__ pos, const float* __restrict__ vel,
    const float2* __restrict__ partial, const float* __restrict__ dtp,
    float* __restrict__ out)
{
    __shared__ float2 red[4][64];

    const int lane = threadIdx.x & 63;          // particle within block
    const int w    = threadIdx.x >> 6;          // wave id 0..3
    const int i    = blockIdx.x * 64 + lane;

    const int c0 = w * (JCHUNKS / 4);
    float ax = 0.f, ay = 0.f;
#pragma unroll 8
    for (int jc = c0; jc < c0 + JCHUNKS / 4; ++jc) {
        const float2 p = partial[jc * N_TOTAL + i];
        ax += p.x;
        ay += p.y;
    }
    red[w][lane] = make_float2(ax, ay);
    __syncthreads();

    if (w == 0) {
        const float2 r1 = red[1][lane];
        const float2 r2 = red[2][lane];
        const float2 r3 = red[3][lane];
        ax += r1.x + r2.x + r3.x;
        ay += r1.y + r2.y + r3.y;

        const float dt = dtp[0];
        const float vx = vel[i * 2 + 0] + ax * dt;
        const float vy = vel[i * 2 + 1] + ay * dt;
        const float px = pos[i * 2 + 0] + vx * dt;
        const float py = pos[i * 2 + 1] + vy * dt;

        out[i * 2 + 0] = px;                    // pos_new
        out[i * 2 + 1] = py;
        out[2 * N_TOTAL + i * 2 + 0] = vx;      // vel_new
        out[2 * N_TOTAL + i * 2 + 1] = vy;
    }
}

// ---------------------------------------------------------------------------
// Kernel 3: marble-vs-eater proximity. Reads pos_new from out (same stream ->
// ordered after integrate). Writes 1.0/0.0 at out + 4*N_TOTAL.
// ---------------------------------------------------------------------------
__global__ __launch_bounds__(BLOCK) void eaten_kernel(
    const float* __restrict__ out_state, const int* __restrict__ eater_idx,
    const float* __restrict__ eater_radius, float* __restrict__ out_eaten)
{
    __shared__ float ex[N_EATERS], ey[N_EATERS], er2[N_EATERS];
    if (threadIdx.x < N_EATERS) {
        const int idx = eater_idx[threadIdx.x];
        ex[threadIdx.x] = out_state[idx * 2 + 0];
        ey[threadIdx.x] = out_state[idx * 2 + 1];
        const float r = eater_radius[threadIdx.x];
        er2[threadIdx.x] = r * r;
    }
    __syncthreads();

    const int m = blockIdx.x * blockDim.x + threadIdx.x;
    const float mx = out_state[(N_NODES + m) * 2 + 0];
    const float my = out_state[(N_NODES + m) * 2 + 1];

    bool any = false;
#pragma unroll
    for (int e = 0; e < N_EATERS; ++e) {
        const float dx = mx - ex[e];
        const float dy = my - ey[e];
        any = any || (dx * dx + dy * dy <= er2[e]);
    }
    out_eaten[m] = any ? 1.0f : 0.0f;
}

extern "C" void kernel_launch(void* const* d_in, const int* in_sizes, int n_in,
                              void* d_out, int out_size, void* d_ws, size_t ws_size,
                              hipStream_t stream) {
    const float* pos  = (const float*)d_in[0];   // (4096, 2)
    const float* vel  = (const float*)d_in[1];   // (4096, 2)
    const float* mass = (const float*)d_in[2];   // (4096,)
    const int*   eidx = (const int*)d_in[3];     // (64,)
    const float* erad = (const float*)d_in[4];   // (64,)
    const float* dt   = (const float*)d_in[5];   // (1,)

    float* out      = (float*)d_out;             // 16384 state + 3072 eaten
    float2* partial = (float2*)d_ws;             // 128*4096 float2 = 4 MB

    dim3 g1(N_TOTAL / BLOCK, JCHUNKS);           // (16, 128)
    force_partial<<<g1, BLOCK, 0, stream>>>((const float2*)pos, mass, partial);
    integrate<<<N_TOTAL / 64, BLOCK, 0, stream>>>(pos, vel, partial, dt, out);
    eaten_kernel<<<N_MARBLES / BLOCK, BLOCK, 0, stream>>>(out, eidx, erad,
                                                          out + 4 * N_TOTAL);
}

// Round 6
// 77.725 us; speedup vs baseline: 1.0237x; 1.0237x over previous
//
#include <hip/hip_runtime.h>

#define N_TOTAL   4096
#define N_NODES   1024
#define N_MARBLES 3072
#define N_EATERS  64
#define EPS       1e-6f
#define BLOCK     256
#define JCHUNK    64                  // j's per force block
#define JCHUNKS   (N_TOTAL / JCHUNK) // 64

// ---------------------------------------------------------------------------
// Kernel 1: partial accelerations.
// grid = (16, 64), block = 256 -> 1024 blocks = 4 blocks/CU = 4 waves/SIMD.
// Issue-bound at this occupancy (measured r4 vs r5: more waves + more partial
// traffic regressed). j is wave-uniform -> s_load_dwordx2 for pos. d2==0
// pairs contribute exactly 0 (dx=dy=0, finite w), so no mask needed.
// ---------------------------------------------------------------------------
__global__ __launch_bounds__(BLOCK) void force_partial(
    const float2* __restrict__ pos2, const float* __restrict__ mass,
    float2* __restrict__ partial)
{
    const int i  = blockIdx.x * BLOCK + threadIdx.x;
    const int j0 = blockIdx.y * JCHUNK;

    const float2 pi = pos2[i];
    float ax = 0.f, ay = 0.f;

#pragma unroll 16
    for (int j = j0; j < j0 + JCHUNK; ++j) {
        const float2 pj = pos2[j];               // uniform -> s_load_dwordx2
        const float dx = pj.x - pi.x;
        const float dy = pj.y - pi.y;
        const float t  = fmaf(dx, dx, fmaf(dy, dy, EPS));  // d2 + EPS
        const float r  = rsqrtf(t);
        const float w  = r * r * r * mass[j];    // m_j * t^{-1.5}
        ax = fmaf(w, dx, ax);
        ay = fmaf(w, dy, ay);
    }

    partial[blockIdx.y * N_TOTAL + i] = make_float2(ax, ay);
}

// ---------------------------------------------------------------------------
// Kernel 2: integrate. grid = 64 blocks x 256 threads; each block owns 64
// particles. Wave t (of 4) sums partial chunks [16t, 16t+16) for all 64
// particles with coalesced float2 reads; LDS-reduce 4 -> 1; wave 0 does the
// Euler step and writes state_new = [pos_new; vel_new] with float2 stores.
// ---------------------------------------------------------------------------
__global__ __launch_bounds__(BLOCK) void integrate(
    const float2* __restrict__ pos2, const float2* __restrict__ vel2,
    const float2* __restrict__ partial, const float* __restrict__ dtp,
    float2* __restrict__ out2)
{
    __shared__ float2 red[4][64];

    const int lane = threadIdx.x & 63;          // particle within block
    const int w    = threadIdx.x >> 6;          // wave id 0..3
    const int i    = blockIdx.x * 64 + lane;

    float ax = 0.f, ay = 0.f;
#pragma unroll 16
    for (int jc = w * 16; jc < w * 16 + 16; ++jc) {
        const float2 p = partial[jc * N_TOTAL + i];
        ax += p.x;
        ay += p.y;
    }
    red[w][lane] = make_float2(ax, ay);
    __syncthreads();

    if (w == 0) {
        const float2 r1 = red[1][lane];
        const float2 r2 = red[2][lane];
        const float2 r3 = red[3][lane];
        ax += r1.x + r2.x + r3.x;
        ay += r1.y + r2.y + r3.y;

        const float dt = dtp[0];
        const float2 v = vel2[i];
        const float2 p = pos2[i];
        const float vx = v.x + ax * dt;
        const float vy = v.y + ay * dt;
        const float px = p.x + vx * dt;
        const float py = p.y + vy * dt;

        out2[i]           = make_float2(px, py);  // pos_new
        out2[N_TOTAL + i] = make_float2(vx, vy);  // vel_new
    }
}

// ---------------------------------------------------------------------------
// Kernel 3: marble-vs-eater proximity. Reads pos_new from out (same stream ->
// ordered after integrate). Writes 1.0/0.0 at out + 4*N_TOTAL.
// ---------------------------------------------------------------------------
__global__ __launch_bounds__(BLOCK) void eaten_kernel(
    const float2* __restrict__ out_pos2, const int* __restrict__ eater_idx,
    const float* __restrict__ eater_radius, float* __restrict__ out_eaten)
{
    __shared__ float ex[N_EATERS], ey[N_EATERS], er2[N_EATERS];
    if (threadIdx.x < N_EATERS) {
        const float2 ep = out_pos2[eater_idx[threadIdx.x]];
        ex[threadIdx.x] = ep.x;
        ey[threadIdx.x] = ep.y;
        const float r = eater_radius[threadIdx.x];
        er2[threadIdx.x] = r * r;
    }
    __syncthreads();

    const int m = blockIdx.x * blockDim.x + threadIdx.x;
    const float2 mp = out_pos2[N_NODES + m];

    bool any = false;
#pragma unroll
    for (int e = 0; e < N_EATERS; ++e) {
        const float dx = mp.x - ex[e];
        const float dy = mp.y - ey[e];
        any = any || (dx * dx + dy * dy <= er2[e]);
    }
    out_eaten[m] = any ? 1.0f : 0.0f;
}

extern "C" void kernel_launch(void* const* d_in, const int* in_sizes, int n_in,
                              void* d_out, int out_size, void* d_ws, size_t ws_size,
                              hipStream_t stream) {
    const float* pos  = (const float*)d_in[0];   // (4096, 2)
    const float* vel  = (const float*)d_in[1];   // (4096, 2)
    const float* mass = (const float*)d_in[2];   // (4096,)
    const int*   eidx = (const int*)d_in[3];     // (64,)
    const float* erad = (const float*)d_in[4];   // (64,)
    const float* dt   = (const float*)d_in[5];   // (1,)

    float* out      = (float*)d_out;             // 16384 state + 3072 eaten
    float2* partial = (float2*)d_ws;             // 64*4096 float2 = 2 MB

    dim3 g1(N_TOTAL / BLOCK, JCHUNKS);           // (16, 64)
    force_partial<<<g1, BLOCK, 0, stream>>>((const float2*)pos, mass, partial);
    integrate<<<N_TOTAL / 64, BLOCK, 0, stream>>>(
        (const float2*)pos, (const float2*)vel, partial, dt, (float2*)out);
    eaten_kernel<<<N_MARBLES / BLOCK, BLOCK, 0, stream>>>(
        (const float2*)out, eidx, erad, out + 4 * N_TOTAL);
}